// Round 1
// baseline (47.028 us; speedup 1.0000x reference)
//
#include <hip/hip_runtime.h>

// KalmanStaticFilter: per-row linear recurrence s_{t+1} = M s_t + c z_t
//   M = [[1-a-b, 1], [-b, 1]], c = [a+b, b], output x_t = p_t + a(z_t - p_t)
// Parallelized via affine-map scan: wave per row, 64 lanes x 32-elem chunks
// per 2048-wide section, Kogge-Stone shuffle scan of (A,b) pairs.

#define A_CONST 0.85f
#define B_CONST 0.005f

constexpr int ROWS  = 4096;
constexpr int T     = 8192;
constexpr int W     = 2048;      // section width
constexpr int L     = 32;        // per-lane chunk length
constexpr int NSEC  = T / W;     // 4
constexpr int STRIDE = 33;       // padded LDS chunk stride (bank-conflict-free)

__global__ __launch_bounds__(256)
void kalman_kernel(const float* __restrict__ Z, float* __restrict__ X) {
    const int wave = threadIdx.x >> 6;
    const int lane = threadIdx.x & 63;
    const int row  = blockIdx.x * 4 + wave;

    __shared__ float lds[4][64 * STRIDE];   // 4 waves * 2112 floats = 33792 B
    float* buf = lds[wave];

    const float* Zr = Z + (size_t)row * T;
    float*       Xr = X + (size_t)row * T;

    // A32 = M^32 via repeated squaring (f64 for accuracy, negligible cost)
    double a00 = 1.0 - (double)A_CONST - (double)B_CONST, a01 = 1.0;
    double a10 = -(double)B_CONST,                        a11 = 1.0;
    #pragma unroll
    for (int i = 0; i < 5; ++i) {
        double n00 = a00*a00 + a01*a10;
        double n01 = a00*a01 + a01*a11;
        double n10 = a10*a00 + a11*a10;
        double n11 = a10*a01 + a11*a11;
        a00 = n00; a01 = n01; a10 = n10; a11 = n11;
    }
    const float A32_00 = (float)a00, A32_01 = (float)a01;
    const float A32_10 = (float)a10, A32_11 = (float)a11;

    // initial state: p0 = Z[row][0], v0 = 0
    float ps = Zr[0];
    float vs = 0.0f;

    for (int sec = 0; sec < NSEC; ++sec) {
        // ---- stage section into LDS (coalesced float4) ----
        const float4* src = (const float4*)(Zr + sec * W);
        #pragma unroll
        for (int i = 0; i < W / 4 / 64; ++i) {          // 8 iterations
            int f = i * 64 + lane;
            float4 v4 = src[f];
            int c = f >> 3;                // chunk
            int j = (f & 7) << 2;          // position within chunk
            float* p = buf + c * STRIDE + j;
            p[0] = v4.x; p[1] = v4.y; p[2] = v4.z; p[3] = v4.w;
        }
        __syncthreads();

        // ---- pass A: per-lane chunk offset b (run from s = (0,0)) ----
        float bp, bv;
        {
            float p = 0.0f, v = 0.0f;
            const float* zc = buf + lane * STRIDE;
            #pragma unroll
            for (int j = 0; j < L; ++j) {
                float z    = zc[j];
                float diff = z - p;
                float x    = p + A_CONST * diff;
                v += B_CONST * diff;
                p  = x + v;
            }
            bp = p; bv = v;
        }

        // ---- Kogge-Stone inclusive scan of affine maps across 64 lanes ----
        float sA00 = A32_00, sA01 = A32_01, sA10 = A32_10, sA11 = A32_11;
        float sb0 = bp, sb1 = bv;
        #pragma unroll
        for (int d = 1; d < 64; d <<= 1) {
            float oA00 = __shfl_up(sA00, d);
            float oA01 = __shfl_up(sA01, d);
            float oA10 = __shfl_up(sA10, d);
            float oA11 = __shfl_up(sA11, d);
            float ob0  = __shfl_up(sb0,  d);
            float ob1  = __shfl_up(sb1,  d);
            if (lane >= d) {
                // compose: own ∘ other   (other is the earlier segment)
                float n00 = sA00*oA00 + sA01*oA10;
                float n01 = sA00*oA01 + sA01*oA11;
                float n10 = sA10*oA00 + sA11*oA10;
                float n11 = sA10*oA01 + sA11*oA11;
                float nb0 = sA00*ob0 + sA01*ob1 + sb0;
                float nb1 = sA10*ob0 + sA11*ob1 + sb1;
                sA00 = n00; sA01 = n01; sA10 = n10; sA11 = n11;
                sb0 = nb0; sb1 = nb1;
            }
        }

        // exclusive prefix (lane 0 = identity)
        float eA00 = __shfl_up(sA00, 1);
        float eA01 = __shfl_up(sA01, 1);
        float eA10 = __shfl_up(sA10, 1);
        float eA11 = __shfl_up(sA11, 1);
        float eb0  = __shfl_up(sb0,  1);
        float eb1  = __shfl_up(sb1,  1);
        if (lane == 0) { eA00 = 1.f; eA01 = 0.f; eA10 = 0.f; eA11 = 1.f; eb0 = 0.f; eb1 = 0.f; }

        // lane-63 inclusive = full section map (for next section's start)
        float iA00 = __shfl(sA00, 63);
        float iA01 = __shfl(sA01, 63);
        float iA10 = __shfl(sA10, 63);
        float iA11 = __shfl(sA11, 63);
        float ib0  = __shfl(sb0,  63);
        float ib1  = __shfl(sb1,  63);

        // ---- pass B: replay chunk with exact entry state, overwrite LDS ----
        {
            float p = eA00*ps + eA01*vs + eb0;
            float v = eA10*ps + eA11*vs + eb1;
            float* zc = buf + lane * STRIDE;
            #pragma unroll
            for (int j = 0; j < L; ++j) {
                float z    = zc[j];
                float diff = z - p;
                float x    = p + A_CONST * diff;
                v += B_CONST * diff;
                p  = x + v;
                zc[j] = x;
            }
        }

        // advance section-start state
        {
            float np = iA00*ps + iA01*vs + ib0;
            float nv = iA10*ps + iA11*vs + ib1;
            ps = np; vs = nv;
        }

        __syncthreads();

        // ---- unload: coalesced float4 store ----
        float4* dst = (float4*)(Xr + sec * W);
        #pragma unroll
        for (int i = 0; i < W / 4 / 64; ++i) {
            int f = i * 64 + lane;
            int c = f >> 3;
            int j = (f & 7) << 2;
            const float* p = buf + c * STRIDE + j;
            dst[f] = make_float4(p[0], p[1], p[2], p[3]);
        }
        __syncthreads();   // protect LDS before next section's staging
    }
}

extern "C" void kernel_launch(void* const* d_in, const int* in_sizes, int n_in,
                              void* d_out, int out_size, void* d_ws, size_t ws_size,
                              hipStream_t stream) {
    const float* Z = (const float*)d_in[0];
    float*       X = (float*)d_out;
    dim3 grid(ROWS / 4), block(256);
    hipLaunchKernelGGL(kalman_kernel, grid, block, 0, stream, Z, X);
}

// Round 3
// 45.581 us; speedup vs baseline: 1.0318x; 1.0318x over previous
//
#include <hip/hip_runtime.h>

// KalmanStaticFilter: per-row linear recurrence s_{t+1} = M s_t + c z_t
//   M = [[1-a-b, 1], [-b, 1]], c = [a+b, b], output x_t = p_t + a(z_t - p_t)
// Wave-per-row affine-map scan. R1/R2: single-wave blocks (no cross-row
// barrier coupling), register prefetch of next section, chunk held in regs
// between offset pass and replay pass, nontemporal output stores.

#define A_CONST 0.85f
#define B_CONST 0.005f

typedef float vfloat4 __attribute__((ext_vector_type(4)));  // plain vector for nontemporal builtin

constexpr int ROWS   = 4096;
constexpr int T      = 8192;
constexpr int W      = 2048;     // section width
constexpr int L      = 32;       // per-lane chunk length
constexpr int NSEC   = T / W;    // 4
constexpr int STRIDE = 33;       // padded LDS chunk stride (bank-conflict-free)

__global__ __launch_bounds__(64)
void kalman_kernel(const float* __restrict__ Z, float* __restrict__ X) {
    const int lane = threadIdx.x;        // 0..63, one wave per block
    const int row  = blockIdx.x;

    __shared__ float buf[64 * STRIDE];   // 8448 B per block

    const float* Zr = Z + (size_t)row * T;
    float*       Xr = X + (size_t)row * T;

    // A32 = M^32 via repeated squaring (f64 once, negligible)
    double a00 = 1.0 - (double)A_CONST - (double)B_CONST, a01 = 1.0;
    double a10 = -(double)B_CONST,                        a11 = 1.0;
    #pragma unroll
    for (int i = 0; i < 5; ++i) {
        double n00 = a00*a00 + a01*a10;
        double n01 = a00*a01 + a01*a11;
        double n10 = a10*a00 + a11*a10;
        double n11 = a10*a01 + a11*a11;
        a00 = n00; a01 = n01; a10 = n10; a11 = n11;
    }
    const float A32_00 = (float)a00, A32_01 = (float)a01;
    const float A32_10 = (float)a10, A32_11 = (float)a11;

    float ps = Zr[0];    // p0 = Z[row][0]
    float vs = 0.0f;

    // prologue: prefetch section 0 into registers
    float4 r[8];
    {
        const float4* src = (const float4*)Zr;
        #pragma unroll
        for (int i = 0; i < 8; ++i) r[i] = src[i * 64 + lane];
    }

    for (int sec = 0; sec < NSEC; ++sec) {
        // ---- stage prefetched registers into LDS (transpose layout) ----
        #pragma unroll
        for (int i = 0; i < 8; ++i) {
            int f = i * 64 + lane;
            int c = f >> 3;                 // chunk
            int j = (f & 7) << 2;           // pos within chunk
            float* p = buf + c * STRIDE + j;
            p[0] = r[i].x; p[1] = r[i].y; p[2] = r[i].z; p[3] = r[i].w;
        }

        // ---- issue next section's global loads (in flight under compute) ----
        if (sec + 1 < NSEC) {
            const float4* src = (const float4*)(Zr + (sec + 1) * W);
            #pragma unroll
            for (int i = 0; i < 8; ++i) r[i] = src[i * 64 + lane];
        }

        __syncthreads();

        // ---- pass A: per-lane chunk offset from s=(0,0); keep z in regs ----
        float c32[L];
        float bp, bv;
        {
            float p = 0.0f, v = 0.0f;
            const float* zc = buf + lane * STRIDE;
            #pragma unroll
            for (int j = 0; j < L; ++j) {
                float z    = zc[j];
                c32[j]     = z;
                float diff = z - p;
                float x    = p + A_CONST * diff;
                v += B_CONST * diff;
                p  = x + v;
            }
            bp = p; bv = v;
        }

        // ---- Kogge-Stone inclusive scan of affine maps across 64 lanes ----
        float sA00 = A32_00, sA01 = A32_01, sA10 = A32_10, sA11 = A32_11;
        float sb0 = bp, sb1 = bv;
        #pragma unroll
        for (int d = 1; d < 64; d <<= 1) {
            float oA00 = __shfl_up(sA00, d);
            float oA01 = __shfl_up(sA01, d);
            float oA10 = __shfl_up(sA10, d);
            float oA11 = __shfl_up(sA11, d);
            float ob0  = __shfl_up(sb0,  d);
            float ob1  = __shfl_up(sb1,  d);
            if (lane >= d) {
                float n00 = sA00*oA00 + sA01*oA10;
                float n01 = sA00*oA01 + sA01*oA11;
                float n10 = sA10*oA00 + sA11*oA10;
                float n11 = sA10*oA01 + sA11*oA11;
                float nb0 = sA00*ob0 + sA01*ob1 + sb0;
                float nb1 = sA10*ob0 + sA11*ob1 + sb1;
                sA00 = n00; sA01 = n01; sA10 = n10; sA11 = n11;
                sb0 = nb0; sb1 = nb1;
            }
        }

        // exclusive prefix (lane 0 = identity)
        float eA00 = __shfl_up(sA00, 1);
        float eA01 = __shfl_up(sA01, 1);
        float eA10 = __shfl_up(sA10, 1);
        float eA11 = __shfl_up(sA11, 1);
        float eb0  = __shfl_up(sb0,  1);
        float eb1  = __shfl_up(sb1,  1);
        if (lane == 0) { eA00 = 1.f; eA01 = 0.f; eA10 = 0.f; eA11 = 1.f; eb0 = 0.f; eb1 = 0.f; }

        // lane-63 inclusive = full section map (next section's start state)
        float iA00 = __shfl(sA00, 63);
        float iA01 = __shfl(sA01, 63);
        float iA10 = __shfl(sA10, 63);
        float iA11 = __shfl(sA11, 63);
        float ib0  = __shfl(sb0,  63);
        float ib1  = __shfl(sb1,  63);

        // ---- pass B: replay chunk from regs with exact entry state ----
        {
            float p = eA00*ps + eA01*vs + eb0;
            float v = eA10*ps + eA11*vs + eb1;
            float* zc = buf + lane * STRIDE;
            #pragma unroll
            for (int j = 0; j < L; ++j) {
                float z    = c32[j];
                float diff = z - p;
                float x    = p + A_CONST * diff;
                v += B_CONST * diff;
                p  = x + v;
                zc[j] = x;
            }
        }

        // advance section-start state
        {
            float np = iA00*ps + iA01*vs + ib0;
            float nv = iA10*ps + iA11*vs + ib1;
            ps = np; vs = nv;
        }

        __syncthreads();

        // ---- unload: coalesced nontemporal float4 stores ----
        {
            vfloat4* dst = (vfloat4*)(Xr + sec * W);
            #pragma unroll
            for (int i = 0; i < 8; ++i) {
                int f = i * 64 + lane;
                int c = f >> 3;
                int j = (f & 7) << 2;
                const float* p = buf + c * STRIDE + j;
                vfloat4 v4 = { p[0], p[1], p[2], p[3] };
                __builtin_nontemporal_store(v4, dst + f);
            }
        }

        __syncthreads();   // protect LDS before next section's staging
    }
}

extern "C" void kernel_launch(void* const* d_in, const int* in_sizes, int n_in,
                              void* d_out, int out_size, void* d_ws, size_t ws_size,
                              hipStream_t stream) {
    const float* Z = (const float*)d_in[0];
    float*       X = (float*)d_out;
    dim3 grid(ROWS), block(64);
    hipLaunchKernelGGL(kalman_kernel, grid, block, 0, stream, Z, X);
}